// Round 2
// baseline (819.093 us; speedup 1.0000x reference)
//
#include <hip/hip_runtime.h>

typedef unsigned short ushortT;
typedef __attribute__((ext_vector_type(8))) short short8;
typedef __attribute__((ext_vector_type(4))) short short4v;

__device__ __forceinline__ float bf2f(ushortT u) {
    unsigned int x = ((unsigned int)u) << 16;
    return __builtin_bit_cast(float, x);
}
__device__ __forceinline__ ushortT f2bf(float f) {
    unsigned int x = __builtin_bit_cast(unsigned int, f);
    unsigned int r = (x + 0x7FFFu + ((x >> 16) & 1u)) >> 16;
    return (ushortT)r;
}

// ---------------------------------------------------------------------------
// 1) fmap [128][1024][196] f32  ->  fmapT [128][196][1024] bf16 (channel-last)
// ---------------------------------------------------------------------------
__global__ __launch_bounds__(256)
void transpose_fmap(const float* __restrict__ fmap, ushortT* __restrict__ fT)
{
    __shared__ ushortT tile[196][66];   // +2 pad breaks bank conflicts
    const int b  = blockIdx.x >> 4;
    const int c0 = (blockIdx.x & 15) << 6;   // 64 channels per block
    const float* src = fmap + ((size_t)b * 1024 + c0) * 196;
    for (int idx = threadIdx.x; idx < 64 * 196; idx += 256) {
        int cl = idx / 196, hw = idx - cl * 196;
        tile[hw][cl] = f2bf(src[cl * 196 + hw]);
    }
    __syncthreads();
    ushortT* dst = fT + (size_t)b * 196 * 1024 + c0;
    for (int idx = threadIdx.x; idx < 196 * 64; idx += 256) {
        int hw = idx >> 6, cl = idx & 63;
        dst[hw * 1024 + cl] = tile[hw][cl];
    }
}

// ---------------------------------------------------------------------------
// 2) Wct[c][o] = sum_m w_c1[m][c] * w_c2[o][m]   (folded 1x1 convs, [1024][256])
// ---------------------------------------------------------------------------
__global__ __launch_bounds__(256)
void build_wct(const float* __restrict__ w_c1, const float* __restrict__ w_c2,
               ushortT* __restrict__ Wct)
{
    const int c = blockIdx.x;     // 1024
    const int o = threadIdx.x;    // 256
    float acc = 0.f;
    for (int m = 0; m < 512; m += 4) {
        float4 wv = *reinterpret_cast<const float4*>(w_c2 + (size_t)o * 512 + m);
        acc = fmaf(wv.x, w_c1[(size_t)(m + 0) * 1024 + c], acc);
        acc = fmaf(wv.y, w_c1[(size_t)(m + 1) * 1024 + c], acc);
        acc = fmaf(wv.z, w_c1[(size_t)(m + 2) * 1024 + c], acc);
        acc = fmaf(wv.w, w_c1[(size_t)(m + 3) * 1024 + c], acc);
    }
    Wct[(size_t)c * 256 + o] = f2bf(acc);
}

// ---------------------------------------------------------------------------
// 3) w_fc1p[hw*256+o][j] = w_fc1[o*9+hw][j]   ([2304][1024] bf16)
// ---------------------------------------------------------------------------
__global__ __launch_bounds__(256)
void permute_fc1(const float* __restrict__ w_fc1, ushortT* __restrict__ wp)
{
    int idx = blockIdx.x * 256 + threadIdx.x;     // 2304*1024 total
    int r = idx >> 10, j = idx & 1023;
    int hw = r >> 8, o = r & 255;
    wp[idx] = f2bf(w_fc1[((size_t)o * 9 + hw) * 1024 + j]);
}

// ---------------------------------------------------------------------------
// 4) ROIAlign: fmapT bf16 -> pooled [4096*9][1024] bf16  (row = k*9 + hw)
// ---------------------------------------------------------------------------
__global__ __launch_bounds__(256)
void roi_align(const ushortT* __restrict__ fT, const float* __restrict__ boxes,
               ushortT* __restrict__ pooled)
{
    const int k = blockIdx.x;       // box id 0..4095
    const int b = k >> 5;
    const float* bx = boxes + (size_t)k * 4;
    float x1 = fminf(fmaxf(bx[0], 0.f), 14.f);
    float y1 = fminf(fmaxf(bx[1], 0.f), 14.f);
    float x2 = fminf(fmaxf(bx[2], 0.f), 14.f);
    float y2 = fminf(fmaxf(bx[3], 0.f), 14.f);
    float roi_w = fmaxf(x2 - x1, 1.f);
    float roi_h = fmaxf(y2 - y1, 1.f);
    float bw = roi_w / 3.0f;
    float bh = roi_h / 3.0f;

    int   ylo[6], xlo[6];
    float wylo[6], wyhi[6], wxlo[6], wxhi[6];
    #pragma unroll
    for (int i = 0; i < 6; ++i) {
        float off = (i & 1) ? 0.75f : 0.25f;
        float pf  = (float)(i >> 1);
        // y axis
        float yc = y1 + pf * bh + off * bh;
        bool  vy = (yc > -1.0f) && (yc < 14.f);
        float cy = fminf(fmaxf(yc, 0.f), 13.f);
        int   lo = (int)floorf(cy); if (lo > 12) lo = 12;
        float fy = cy - (float)lo;
        ylo[i]  = lo;
        wylo[i] = vy ? 1.f - fy : 0.f;
        wyhi[i] = vy ? fy       : 0.f;
        // x axis
        float xc = x1 + pf * bw + off * bw;
        bool  vx = (xc > -1.0f) && (xc < 14.f);
        float cx = fminf(fmaxf(xc, 0.f), 13.f);
        int   lx = (int)floorf(cx); if (lx > 12) lx = 12;
        float fx = cx - (float)lx;
        xlo[i]  = lx;
        wxlo[i] = vx ? 1.f - fx : 0.f;
        wxhi[i] = vx ? fx       : 0.f;
    }

    const ushortT* fb   = fT + (size_t)b * 196 * 1024;
    ushortT*       outp = pooled + (size_t)k * 9 * 1024;
    for (int c = threadIdx.x; c < 1024; c += 256) {
        float acc[3][3] = {};
        #pragma unroll
        for (int i = 0; i < 6; ++i) {
            const ushortT* rlo = fb + (size_t)(ylo[i] * 14) * 1024 + c;
            const ushortT* rhi = rlo + 14 * 1024;
            #pragma unroll
            for (int j = 0; j < 6; ++j) {
                float v00 = bf2f(rlo[(size_t)xlo[j] * 1024]);
                float v01 = bf2f(rlo[(size_t)(xlo[j] + 1) * 1024]);
                float v10 = bf2f(rhi[(size_t)xlo[j] * 1024]);
                float v11 = bf2f(rhi[(size_t)(xlo[j] + 1) * 1024]);
                float top = v00 * wxlo[j] + v01 * wxhi[j];
                float bot = v10 * wxlo[j] + v11 * wxhi[j];
                acc[i >> 1][j >> 1] += top * wylo[i] + bot * wyhi[i];
            }
        }
        #pragma unroll
        for (int p = 0; p < 3; ++p)
            #pragma unroll
            for (int q = 0; q < 3; ++q)
                outp[(size_t)(p * 3 + q) * 1024 + c] = f2bf(acc[p][q] * 0.25f);
    }
}

// ---------------------------------------------------------------------------
// 5) Tiled GEMM: C[M][N] = A[M][K] * B[K][N]  (bf16 in, f32 acc, bf16 out)
//    64x64 tile, 4x4 per thread, LDS-staged (A transposed + padded).
// ---------------------------------------------------------------------------
#define BM 64
#define BN 64
#define BK 32

template<int RELU, int BIAS>
__global__ __launch_bounds__(256)
void gemm_bf(const ushortT* __restrict__ A, const ushortT* __restrict__ B,
             ushortT* __restrict__ C, const float* __restrict__ bias,
             int M, int N, int K)
{
    __shared__ float As[BK][BM + 4];   // stride 68 -> 16B-aligned b128 reads
    __shared__ float Bs[BK][BN];
    const int tid  = threadIdx.x;
    const int row0 = blockIdx.x * BM;
    const int col0 = blockIdx.y * BN;
    const int ty = tid >> 4, tx = tid & 15;
    float acc[4][4] = {};

    const int arow = tid >> 2, ak0 = (tid & 3) * 8;   // A stage: 64 rows x 32 k
    const int brow = tid >> 3, bc0 = (tid & 7) * 8;   // B stage: 32 rows x 64 n
    const ushortT* aptr = A + (size_t)(row0 + arow) * K + ak0;
    const ushortT* bptr = B + (size_t)brow * N + col0 + bc0;

    for (int k0 = 0; k0 < K; k0 += BK) {
        short8 av = *reinterpret_cast<const short8*>(aptr + k0);
        short8 bv = *reinterpret_cast<const short8*>(bptr + (size_t)k0 * N);
        #pragma unroll
        for (int j = 0; j < 8; ++j) As[ak0 + j][arow] = bf2f((ushortT)av[j]);
        #pragma unroll
        for (int j = 0; j < 8; ++j) Bs[brow][bc0 + j] = bf2f((ushortT)bv[j]);
        __syncthreads();
        #pragma unroll
        for (int kk = 0; kk < BK; ++kk) {
            float a[4], b[4];
            #pragma unroll
            for (int i = 0; i < 4; ++i) a[i] = As[kk][ty * 4 + i];
            #pragma unroll
            for (int j = 0; j < 4; ++j) b[j] = Bs[kk][tx * 4 + j];
            #pragma unroll
            for (int i = 0; i < 4; ++i)
                #pragma unroll
                for (int j = 0; j < 4; ++j)
                    acc[i][j] = fmaf(a[i], b[j], acc[i][j]);
        }
        __syncthreads();
    }

    #pragma unroll
    for (int i = 0; i < 4; ++i) {
        int r = row0 + ty * 4 + i;
        short4v ov;
        #pragma unroll
        for (int j = 0; j < 4; ++j) {
            float v = acc[i][j];
            if (BIAS) v += bias[col0 + tx * 4 + j];
            if (RELU) v = fmaxf(v, 0.f);
            ov[j] = (short)f2bf(v);
        }
        *reinterpret_cast<short4v*>(C + (size_t)r * N + col0 + tx * 4) = ov;
    }
}

// ---------------------------------------------------------------------------
// 6) fc2: out[4096][27] f32 = h[4096][1024] @ w[1024][27] + b
// ---------------------------------------------------------------------------
__global__ __launch_bounds__(64)
void fc2_kernel(const ushortT* __restrict__ h, const float* __restrict__ w,
                const float* __restrict__ bias, float* __restrict__ out)
{
    const int r    = blockIdx.x;
    const int lane = threadIdx.x;
    float acc[27];
    #pragma unroll
    for (int j = 0; j < 27; ++j) acc[j] = 0.f;
    const ushortT* hr = h + (size_t)r * 1024;
    for (int k = lane; k < 1024; k += 64) {
        float hv = bf2f(hr[k]);
        const float* wr = w + (size_t)k * 27;
        #pragma unroll
        for (int j = 0; j < 27; ++j) acc[j] = fmaf(hv, wr[j], acc[j]);
    }
    #pragma unroll
    for (int j = 0; j < 27; ++j) {
        #pragma unroll
        for (int off = 32; off; off >>= 1)
            acc[j] += __shfl_down(acc[j], off);
    }
    if (lane == 0) {
        #pragma unroll
        for (int j = 0; j < 27; ++j)
            out[(size_t)r * 27 + j] = acc[j] + bias[j];
    }
}

// ---------------------------------------------------------------------------
extern "C" void kernel_launch(void* const* d_in, const int* in_sizes, int n_in,
                              void* d_out, int out_size, void* d_ws, size_t ws_size,
                              hipStream_t stream)
{
    (void)in_sizes; (void)n_in; (void)out_size; (void)ws_size;
    const float* fmap  = (const float*)d_in[0];
    const float* boxes = (const float*)d_in[1];
    const float* w_c1  = (const float*)d_in[2];
    const float* w_c2  = (const float*)d_in[3];
    const float* w_fc1 = (const float*)d_in[4];
    const float* b_fc1 = (const float*)d_in[5];
    const float* w_fc2 = (const float*)d_in[6];
    const float* b_fc2 = (const float*)d_in[7];
    float* out = (float*)d_out;   // reference output dtype is float32

    // Workspace layout with lifetime aliasing (126 MiB total):
    //   region0: fT (51.4 MB, live k1->roi)   ; ybuf (18.9 MB) aliases it after roi
    //   region1: pooled (75.5 MB, roi->gemm1) ; hbuf (8.4 MB) aliases it after gemm1
    //   region2: Wct (0.5 MB), region3: wp (4.7 MB)
    char* ws = (char*)d_ws;
    ushortT* fT     = (ushortT*)(ws);
    ushortT* ybuf   = (ushortT*)(ws);                      // alias: fT dead after roi_align
    ushortT* pooled = (ushortT*)(ws + 51380224);
    ushortT* hbuf   = (ushortT*)(ws + 51380224);           // alias: pooled dead after gemm1
    ushortT* Wct    = (ushortT*)(ws + 51380224 + 75497472);
    ushortT* wp     = (ushortT*)(ws + 51380224 + 75497472 + 524288);

    hipLaunchKernelGGL(transpose_fmap, dim3(2048), dim3(256), 0, stream, fmap, fT);
    hipLaunchKernelGGL(build_wct,     dim3(1024), dim3(256), 0, stream, w_c1, w_c2, Wct);
    hipLaunchKernelGGL(permute_fc1,   dim3(9216), dim3(256), 0, stream, w_fc1, wp);
    hipLaunchKernelGGL(roi_align,     dim3(4096), dim3(256), 0, stream, fT, boxes, pooled);

    hipLaunchKernelGGL((gemm_bf<0,0>), dim3(576, 4),  dim3(256), 0, stream,
                       pooled, Wct, ybuf, (const float*)nullptr, 36864, 256, 1024);
    hipLaunchKernelGGL((gemm_bf<1,1>), dim3(64, 16),  dim3(256), 0, stream,
                       ybuf, wp, hbuf, b_fc1, 4096, 1024, 2304);
    hipLaunchKernelGGL(fc2_kernel,    dim3(4096), dim3(64), 0, stream,
                       hbuf, w_fc2, b_fc2, out);
}

// Round 3
// 419.050 us; speedup vs baseline: 1.9546x; 1.9546x over previous
//
#include <hip/hip_runtime.h>

typedef unsigned short ushortT;
typedef __attribute__((ext_vector_type(8))) short short8;
typedef __attribute__((ext_vector_type(4))) short short4v;
typedef __attribute__((ext_vector_type(8))) __bf16 bf16x8;
typedef __attribute__((ext_vector_type(4))) float f32x4;

__device__ __forceinline__ float bf2f(ushortT u) {
    unsigned int x = ((unsigned int)u) << 16;
    return __builtin_bit_cast(float, x);
}
__device__ __forceinline__ ushortT f2bf(float f) {
    unsigned int x = __builtin_bit_cast(unsigned int, f);
    unsigned int r = (x + 0x7FFFu + ((x >> 16) & 1u)) >> 16;
    return (ushortT)r;
}

__device__ __forceinline__ void gload_lds16(const void* g, void* l) {
    __builtin_amdgcn_global_load_lds(
        (const __attribute__((address_space(1))) void*)g,
        (__attribute__((address_space(3))) void*)l, 16, 0, 0);
}

// ---------------------------------------------------------------------------
// 1) fmap [128][1024][196] f32  ->  fmapT [128][196][1024] bf16 (channel-last)
// ---------------------------------------------------------------------------
__global__ __launch_bounds__(256)
void transpose_fmap(const float* __restrict__ fmap, ushortT* __restrict__ fT)
{
    __shared__ ushortT tile[196][66];   // +2 pad breaks bank conflicts
    const int b  = blockIdx.x >> 4;
    const int c0 = (blockIdx.x & 15) << 6;   // 64 channels per block
    const float* src = fmap + ((size_t)b * 1024 + c0) * 196;
    for (int idx = threadIdx.x; idx < 64 * 196; idx += 256) {
        int cl = idx / 196, hw = idx - cl * 196;
        tile[hw][cl] = f2bf(src[cl * 196 + hw]);
    }
    __syncthreads();
    ushortT* dst = fT + (size_t)b * 196 * 1024 + c0;
    for (int idx = threadIdx.x; idx < 196 * 64; idx += 256) {
        int hw = idx >> 6, cl = idx & 63;
        dst[hw * 1024 + cl] = tile[hw][cl];
    }
}

// ---------------------------------------------------------------------------
// 2) Wct_t[o][c] = sum_m w_c2[o][m] * w_c1[m][c]   ([256][1024] bf16, B^T form)
//    grid (4 o-tiles, 16 c-tiles), 64x64 out tile, LDS-tiled small GEMM.
// ---------------------------------------------------------------------------
__global__ __launch_bounds__(256)
void build_wct(const float* __restrict__ w_c1, const float* __restrict__ w_c2,
               ushortT* __restrict__ Wct_t)
{
    __shared__ float w2s[64][65];
    __shared__ float w1s[64][65];
    const int o0 = blockIdx.x * 64;
    const int c0 = blockIdx.y * 64;
    const int tid = threadIdx.x;
    const int ty = tid >> 4, tx = tid & 15;
    float acc[4][4] = {};
    for (int m0 = 0; m0 < 512; m0 += 64) {
        #pragma unroll
        for (int c4 = 0; c4 < 4; ++c4) {
            int idx = c4 * 256 + tid;
            int row = idx >> 4, f4 = idx & 15;
            float4 v = *reinterpret_cast<const float4*>(w_c2 + (size_t)(o0 + row) * 512 + m0 + f4 * 4);
            w2s[row][f4*4+0] = v.x; w2s[row][f4*4+1] = v.y;
            w2s[row][f4*4+2] = v.z; w2s[row][f4*4+3] = v.w;
            float4 u = *reinterpret_cast<const float4*>(w_c1 + (size_t)(m0 + row) * 1024 + c0 + f4 * 4);
            w1s[row][f4*4+0] = u.x; w1s[row][f4*4+1] = u.y;
            w1s[row][f4*4+2] = u.z; w1s[row][f4*4+3] = u.w;
        }
        __syncthreads();
        for (int m = 0; m < 64; ++m) {
            float a[4], b[4];
            #pragma unroll
            for (int i = 0; i < 4; ++i) a[i] = w2s[ty*4+i][m];
            #pragma unroll
            for (int j = 0; j < 4; ++j) b[j] = w1s[m][tx*4+j];
            #pragma unroll
            for (int i = 0; i < 4; ++i)
                #pragma unroll
                for (int j = 0; j < 4; ++j) acc[i][j] = fmaf(a[i], b[j], acc[i][j]);
        }
        __syncthreads();
    }
    #pragma unroll
    for (int i = 0; i < 4; ++i) {
        short4v ov;
        #pragma unroll
        for (int j = 0; j < 4; ++j) ov[j] = (short)f2bf(acc[i][j]);
        *reinterpret_cast<short4v*>(Wct_t + (size_t)(o0 + ty*4 + i) * 1024 + c0 + tx*4) = ov;
    }
}

// ---------------------------------------------------------------------------
// 3) wp_t[j][hw*256+o] = w_fc1[o*9+hw][j]   ([1024][2304] bf16, B^T form)
//    grid (36 ci-tiles, 16 j-tiles); LDS-transposed so both sides coalesce.
// ---------------------------------------------------------------------------
__global__ __launch_bounds__(256)
void permute_fc1(const float* __restrict__ w_fc1, ushortT* __restrict__ wpt)
{
    __shared__ float tile[64][65];
    const int ci0 = blockIdx.x * 64;
    const int j0  = blockIdx.y * 64;
    const int hw  = ci0 >> 8;
    const int o0  = ci0 & 255;
    const int tid = threadIdx.x;
    #pragma unroll
    for (int c4 = 0; c4 < 4; ++c4) {
        int idx = c4 * 256 + tid;
        int row = idx >> 4;           // o offset 0..63
        int f4  = idx & 15;
        float4 v = *reinterpret_cast<const float4*>(
            w_fc1 + (size_t)((o0 + row) * 9 + hw) * 1024 + j0 + f4 * 4);
        tile[row][f4*4+0] = v.x; tile[row][f4*4+1] = v.y;
        tile[row][f4*4+2] = v.z; tile[row][f4*4+3] = v.w;
    }
    __syncthreads();
    #pragma unroll
    for (int c4 = 0; c4 < 4; ++c4) {
        int idx = c4 * 256 + tid;
        int j   = idx >> 4;           // 0..63
        int og  = idx & 15;           // o group of 4
        short4v ov;
        #pragma unroll
        for (int i = 0; i < 4; ++i) ov[i] = (short)f2bf(tile[og*4+i][j]);
        *reinterpret_cast<short4v*>(wpt + (size_t)(j0 + j) * 2304 + ci0 + og*4) = ov;
    }
}

// ---------------------------------------------------------------------------
// 4) ROIAlign: fmapT bf16 -> pooled [4096*9][1024] bf16  (row = k*9 + hw)
// ---------------------------------------------------------------------------
__global__ __launch_bounds__(256)
void roi_align(const ushortT* __restrict__ fT, const float* __restrict__ boxes,
               ushortT* __restrict__ pooled)
{
    const int k = blockIdx.x;       // box id 0..4095
    const int b = k >> 5;
    const float* bx = boxes + (size_t)k * 4;
    float x1 = fminf(fmaxf(bx[0], 0.f), 14.f);
    float y1 = fminf(fmaxf(bx[1], 0.f), 14.f);
    float x2 = fminf(fmaxf(bx[2], 0.f), 14.f);
    float y2 = fminf(fmaxf(bx[3], 0.f), 14.f);
    float roi_w = fmaxf(x2 - x1, 1.f);
    float roi_h = fmaxf(y2 - y1, 1.f);
    float bw = roi_w / 3.0f;
    float bh = roi_h / 3.0f;

    int   ylo[6], xlo[6];
    float wylo[6], wyhi[6], wxlo[6], wxhi[6];
    #pragma unroll
    for (int i = 0; i < 6; ++i) {
        float off = (i & 1) ? 0.75f : 0.25f;
        float pf  = (float)(i >> 1);
        float yc = y1 + pf * bh + off * bh;
        bool  vy = (yc > -1.0f) && (yc < 14.f);
        float cy = fminf(fmaxf(yc, 0.f), 13.f);
        int   lo = (int)floorf(cy); if (lo > 12) lo = 12;
        float fy = cy - (float)lo;
        ylo[i]  = lo;
        wylo[i] = vy ? 1.f - fy : 0.f;
        wyhi[i] = vy ? fy       : 0.f;
        float xc = x1 + pf * bw + off * bw;
        bool  vx = (xc > -1.0f) && (xc < 14.f);
        float cx = fminf(fmaxf(xc, 0.f), 13.f);
        int   lx = (int)floorf(cx); if (lx > 12) lx = 12;
        float fx = cx - (float)lx;
        xlo[i]  = lx;
        wxlo[i] = vx ? 1.f - fx : 0.f;
        wxhi[i] = vx ? fx       : 0.f;
    }

    const ushortT* fb   = fT + (size_t)b * 196 * 1024;
    ushortT*       outp = pooled + (size_t)k * 9 * 1024;
    for (int c = threadIdx.x; c < 1024; c += 256) {
        float acc[3][3] = {};
        #pragma unroll
        for (int i = 0; i < 6; ++i) {
            const ushortT* rlo = fb + (size_t)(ylo[i] * 14) * 1024 + c;
            const ushortT* rhi = rlo + 14 * 1024;
            #pragma unroll
            for (int j = 0; j < 6; ++j) {
                float v00 = bf2f(rlo[(size_t)xlo[j] * 1024]);
                float v01 = bf2f(rlo[(size_t)(xlo[j] + 1) * 1024]);
                float v10 = bf2f(rhi[(size_t)xlo[j] * 1024]);
                float v11 = bf2f(rhi[(size_t)(xlo[j] + 1) * 1024]);
                float top = v00 * wxlo[j] + v01 * wxhi[j];
                float bot = v10 * wxlo[j] + v11 * wxhi[j];
                acc[i >> 1][j >> 1] += top * wylo[i] + bot * wyhi[i];
            }
        }
        #pragma unroll
        for (int p = 0; p < 3; ++p)
            #pragma unroll
            for (int q = 0; q < 3; ++q)
                outp[(size_t)(p * 3 + q) * 1024 + c] = f2bf(acc[p][q] * 0.25f);
    }
}

// ---------------------------------------------------------------------------
// 5) MFMA GEMM (m97 structure): C[M][N] = A[M][K] * Bt[N][K]^T
//    128x128 tile, BK=32, 4 waves (2x2 of 64x64), global_load_lds staging,
//    mfma_f32_16x16x32_bf16, f32 accum, bf16 out (+bias/relu epilogue).
// ---------------------------------------------------------------------------
template<int RELU, int BIAS>
__global__ __launch_bounds__(256)
void gemm_mfma(const ushortT* __restrict__ A, const ushortT* __restrict__ Bt,
               ushortT* __restrict__ C, const float* __restrict__ bias,
               int M, int N, int K)
{
    __shared__ ushortT As[128 * 32];
    __shared__ ushortT Bs[128 * 32];
    const int tid  = threadIdx.x;
    const int lane = tid & 63;
    const int wid  = tid >> 6;
    const int wr   = wid >> 1;        // wave row 0..1 (64 rows each)
    const int wc   = wid & 1;         // wave col 0..1
    const size_t row0 = (size_t)blockIdx.x * 128;
    const size_t col0 = (size_t)blockIdx.y * 128;

    // staging: thread t owns 16B chunk t and t+256 of each 8KB tile (linear LDS)
    const int s_row = tid >> 2;           // 0..63
    const int s_k   = (tid & 3) * 8;
    const ushortT* ag = A  + (row0 + s_row) * K + s_k;
    const ushortT* bg = Bt + (col0 + s_row) * K + s_k;
    ushortT* al = &As[s_row * 32 + s_k];
    ushortT* bl = &Bs[s_row * 32 + s_k];

    f32x4 acc[4][4];
    #pragma unroll
    for (int i = 0; i < 4; ++i)
        #pragma unroll
        for (int j = 0; j < 4; ++j) acc[i][j] = (f32x4){0.f, 0.f, 0.f, 0.f};

    const int fr = lane & 15;          // fragment row (A) / col (B)
    const int kg = (lane >> 4) * 8;    // k offset within BK

    for (int k0 = 0; k0 < K; k0 += 32) {
        gload_lds16(ag + k0,                  al);
        gload_lds16(ag + k0 + (size_t)64 * K, al + 64 * 32);
        gload_lds16(bg + k0,                  bl);
        gload_lds16(bg + k0 + (size_t)64 * K, bl + 64 * 32);
        __syncthreads();
        bf16x8 a[4], b[4];
        #pragma unroll
        for (int m = 0; m < 4; ++m)
            a[m] = *reinterpret_cast<const bf16x8*>(&As[(wr*64 + m*16 + fr) * 32 + kg]);
        #pragma unroll
        for (int n = 0; n < 4; ++n)
            b[n] = *reinterpret_cast<const bf16x8*>(&Bs[(wc*64 + n*16 + fr) * 32 + kg]);
        #pragma unroll
        for (int m = 0; m < 4; ++m)
            #pragma unroll
            for (int n = 0; n < 4; ++n)
                acc[m][n] = __builtin_amdgcn_mfma_f32_16x16x32_bf16(a[m], b[n], acc[m][n], 0, 0, 0);
        __syncthreads();
    }

    const int orow = (lane >> 4) * 4;  // C/D: col=lane&15, row=(lane>>4)*4+j  [m89/m91]
    #pragma unroll
    for (int n = 0; n < 4; ++n) {
        const size_t col = col0 + wc*64 + n*16 + fr;
        float bv = 0.f;
        if (BIAS) bv = bias[col];
        #pragma unroll
        for (int m = 0; m < 4; ++m) {
            const size_t rbase = row0 + wr*64 + m*16 + orow;
            #pragma unroll
            for (int j = 0; j < 4; ++j) {
                float v = acc[m][n][j] + bv;
                if (RELU) v = fmaxf(v, 0.f);
                C[(rbase + j) * N + col] = f2bf(v);
            }
        }
    }
}

// ---------------------------------------------------------------------------
// 6) fc2: out[4096][27] f32 = h[4096][1024] @ w[1024][27] + b
// ---------------------------------------------------------------------------
__global__ __launch_bounds__(64)
void fc2_kernel(const ushortT* __restrict__ h, const float* __restrict__ w,
                const float* __restrict__ bias, float* __restrict__ out)
{
    const int r    = blockIdx.x;
    const int lane = threadIdx.x;
    float acc[27];
    #pragma unroll
    for (int j = 0; j < 27; ++j) acc[j] = 0.f;
    const ushortT* hr = h + (size_t)r * 1024;
    for (int k = lane; k < 1024; k += 64) {
        float hv = bf2f(hr[k]);
        const float* wr = w + (size_t)k * 27;
        #pragma unroll
        for (int j = 0; j < 27; ++j) acc[j] = fmaf(hv, wr[j], acc[j]);
    }
    #pragma unroll
    for (int j = 0; j < 27; ++j) {
        #pragma unroll
        for (int off = 32; off; off >>= 1)
            acc[j] += __shfl_down(acc[j], off);
    }
    if (lane == 0) {
        #pragma unroll
        for (int j = 0; j < 27; ++j)
            out[(size_t)r * 27 + j] = acc[j] + bias[j];
    }
}

// ---------------------------------------------------------------------------
extern "C" void kernel_launch(void* const* d_in, const int* in_sizes, int n_in,
                              void* d_out, int out_size, void* d_ws, size_t ws_size,
                              hipStream_t stream)
{
    (void)in_sizes; (void)n_in; (void)out_size; (void)ws_size;
    const float* fmap  = (const float*)d_in[0];
    const float* boxes = (const float*)d_in[1];
    const float* w_c1  = (const float*)d_in[2];
    const float* w_c2  = (const float*)d_in[3];
    const float* w_fc1 = (const float*)d_in[4];
    const float* b_fc1 = (const float*)d_in[5];
    const float* w_fc2 = (const float*)d_in[6];
    const float* b_fc2 = (const float*)d_in[7];
    float* out = (float*)d_out;   // reference output dtype is float32

    // Workspace layout with lifetime aliasing:
    //   region0: fT (51.4 MB, live transpose->roi) ; ybuf (18.9 MB) aliases after roi
    //   region1: pooled (75.5 MB, roi->gemm1)      ; hbuf (8.4 MB) aliases after gemm1
    //   region2: Wct_t (0.5 MB), region3: wp_t (4.7 MB)
    char* ws = (char*)d_ws;
    ushortT* fT     = (ushortT*)(ws);
    ushortT* ybuf   = (ushortT*)(ws);                      // alias: fT dead after roi_align
    ushortT* pooled = (ushortT*)(ws + 51380224);
    ushortT* hbuf   = (ushortT*)(ws + 51380224);           // alias: pooled dead after gemm1
    ushortT* Wct_t  = (ushortT*)(ws + 51380224 + 75497472);
    ushortT* wp_t   = (ushortT*)(ws + 51380224 + 75497472 + 524288);

    hipLaunchKernelGGL(transpose_fmap, dim3(2048), dim3(256), 0, stream, fmap, fT);
    hipLaunchKernelGGL(build_wct,      dim3(4, 16),  dim3(256), 0, stream, w_c1, w_c2, Wct_t);
    hipLaunchKernelGGL(permute_fc1,    dim3(36, 16), dim3(256), 0, stream, w_fc1, wp_t);
    hipLaunchKernelGGL(roi_align,      dim3(4096),   dim3(256), 0, stream, fT, boxes, pooled);

    // GEMM1: [36864 x 256] = pooled[36864 x 1024] * Wct_t[256 x 1024]^T
    hipLaunchKernelGGL((gemm_mfma<0,0>), dim3(288, 2), dim3(256), 0, stream,
                       pooled, Wct_t, ybuf, (const float*)nullptr, 36864, 256, 1024);
    // GEMM2: [4096 x 1024] = ybuf[4096 x 2304] * wp_t[1024 x 2304]^T  (+bias, relu)
    hipLaunchKernelGGL((gemm_mfma<1,1>), dim3(32, 8),  dim3(256), 0, stream,
                       ybuf, wp_t, hbuf, b_fc1, 4096, 1024, 2304);
    hipLaunchKernelGGL(fc2_kernel,     dim3(4096), dim3(64), 0, stream,
                       hbuf, w_fc2, b_fc2, out);
}

// Round 4
// 216.329 us; speedup vs baseline: 3.7863x; 1.9371x over previous
//
#include <hip/hip_runtime.h>

typedef unsigned short ushortT;
typedef __attribute__((ext_vector_type(8))) short short8;
typedef __attribute__((ext_vector_type(4))) short short4v;
typedef __attribute__((ext_vector_type(8))) __bf16 bf16x8;
typedef __attribute__((ext_vector_type(4))) float f32x4;

__device__ __forceinline__ float bf2f(ushortT u) {
    unsigned int x = ((unsigned int)u) << 16;
    return __builtin_bit_cast(float, x);
}
__device__ __forceinline__ ushortT f2bf(float f) {
    unsigned int x = __builtin_bit_cast(unsigned int, f);
    unsigned int r = (x + 0x7FFFu + ((x >> 16) & 1u)) >> 16;
    return (ushortT)r;
}

__device__ __forceinline__ void gload_lds16(const void* g, void* l) {
    __builtin_amdgcn_global_load_lds(
        (const __attribute__((address_space(1))) void*)g,
        (__attribute__((address_space(3))) void*)l, 16, 0, 0);
}

// ---------------------------------------------------------------------------
// 1) Wct_t[o][c] = sum_m w_c2[o][m] * w_c1[m][c]   ([256][1024] bf16, B^T form)
// ---------------------------------------------------------------------------
__global__ __launch_bounds__(256)
void build_wct(const float* __restrict__ w_c1, const float* __restrict__ w_c2,
               ushortT* __restrict__ Wct_t)
{
    __shared__ float w2s[64][65];
    __shared__ float w1s[64][65];
    const int o0 = blockIdx.x * 64;
    const int c0 = blockIdx.y * 64;
    const int tid = threadIdx.x;
    const int ty = tid >> 4, tx = tid & 15;
    float acc[4][4] = {};
    for (int m0 = 0; m0 < 512; m0 += 64) {
        #pragma unroll
        for (int c4 = 0; c4 < 4; ++c4) {
            int idx = c4 * 256 + tid;
            int row = idx >> 4, f4 = idx & 15;
            float4 v = *reinterpret_cast<const float4*>(w_c2 + (size_t)(o0 + row) * 512 + m0 + f4 * 4);
            w2s[row][f4*4+0] = v.x; w2s[row][f4*4+1] = v.y;
            w2s[row][f4*4+2] = v.z; w2s[row][f4*4+3] = v.w;
            float4 u = *reinterpret_cast<const float4*>(w_c1 + (size_t)(m0 + row) * 1024 + c0 + f4 * 4);
            w1s[row][f4*4+0] = u.x; w1s[row][f4*4+1] = u.y;
            w1s[row][f4*4+2] = u.z; w1s[row][f4*4+3] = u.w;
        }
        __syncthreads();
        for (int m = 0; m < 64; ++m) {
            float a[4], b[4];
            #pragma unroll
            for (int i = 0; i < 4; ++i) a[i] = w2s[ty*4+i][m];
            #pragma unroll
            for (int j = 0; j < 4; ++j) b[j] = w1s[m][tx*4+j];
            #pragma unroll
            for (int i = 0; i < 4; ++i)
                #pragma unroll
                for (int j = 0; j < 4; ++j) acc[i][j] = fmaf(a[i], b[j], acc[i][j]);
        }
        __syncthreads();
    }
    #pragma unroll
    for (int i = 0; i < 4; ++i) {
        short4v ov;
        #pragma unroll
        for (int j = 0; j < 4; ++j) ov[j] = (short)f2bf(acc[i][j]);
        *reinterpret_cast<short4v*>(Wct_t + (size_t)(o0 + ty*4 + i) * 1024 + c0 + tx*4) = ov;
    }
}

// ---------------------------------------------------------------------------
// 2) wp_t[j][hw*256+o] = w_fc1[o*9+hw][j]   ([1024][2304] bf16, B^T form)
// ---------------------------------------------------------------------------
__global__ __launch_bounds__(256)
void permute_fc1(const float* __restrict__ w_fc1, ushortT* __restrict__ wpt)
{
    __shared__ float tile[64][65];
    const int ci0 = blockIdx.x * 64;
    const int j0  = blockIdx.y * 64;
    const int hw  = ci0 >> 8;
    const int o0  = ci0 & 255;
    const int tid = threadIdx.x;
    #pragma unroll
    for (int c4 = 0; c4 < 4; ++c4) {
        int idx = c4 * 256 + tid;
        int row = idx >> 4;           // o offset 0..63
        int f4  = idx & 15;
        float4 v = *reinterpret_cast<const float4*>(
            w_fc1 + (size_t)((o0 + row) * 9 + hw) * 1024 + j0 + f4 * 4);
        tile[row][f4*4+0] = v.x; tile[row][f4*4+1] = v.y;
        tile[row][f4*4+2] = v.z; tile[row][f4*4+3] = v.w;
    }
    __syncthreads();
    #pragma unroll
    for (int c4 = 0; c4 < 4; ++c4) {
        int idx = c4 * 256 + tid;
        int j   = idx >> 4;           // 0..63
        int og  = idx & 15;           // o group of 4
        short4v ov;
        #pragma unroll
        for (int i = 0; i < 4; ++i) ov[i] = (short)f2bf(tile[og*4+i][j]);
        *reinterpret_cast<short4v*>(wpt + (size_t)(j0 + j) * 2304 + ci0 + og*4) = ov;
    }
}

// ---------------------------------------------------------------------------
// 3) Fused transpose + ROIAlign: fmap f32 [128][1024][196] -> pooled bf16
//    [4096*9][1024].  Block = (image, 64-ch group); LDS tile [196][72] bf16.
//    Thread = (box, 8-ch chunk): 32 boxes x 8 chunks = 256.
// ---------------------------------------------------------------------------
__global__ __launch_bounds__(256)
void roi_align_fused(const float* __restrict__ fmap, const float* __restrict__ boxes,
                     ushortT* __restrict__ pooled)
{
    __shared__ ushortT tile[196][72];   // row stride 144B: 16B-aligned, bank-step 4
    const int b   = blockIdx.x >> 4;        // image 0..127
    const int c0  = (blockIdx.x & 15) << 6; // channel base (64 per block)
    const int tid = threadIdx.x;

    // ---- load + transpose + bf16-convert: fmap[b][c0+c][pos] -> tile[pos][c]
    const float* src = fmap + ((size_t)b * 1024 + c0) * 196;
    for (int item = tid; item < 3136; item += 256) {    // 64 ch * 49 float4
        int c  = item / 49;
        int p4 = (item - c * 49) * 4;
        float4 v = *reinterpret_cast<const float4*>(src + (size_t)c * 196 + p4);
        tile[p4 + 0][c] = f2bf(v.x);
        tile[p4 + 1][c] = f2bf(v.y);
        tile[p4 + 2][c] = f2bf(v.z);
        tile[p4 + 3][c] = f2bf(v.w);
    }
    __syncthreads();

    // ---- per-thread box setup
    const int box = tid >> 3;          // 0..31
    const int ch8 = (tid & 7) << 3;    // 0..56
    const int k   = (b << 5) + box;
    const float* bx = boxes + (size_t)k * 4;
    float x1 = fminf(fmaxf(bx[0], 0.f), 14.f);
    float y1 = fminf(fmaxf(bx[1], 0.f), 14.f);
    float x2 = fminf(fmaxf(bx[2], 0.f), 14.f);
    float y2 = fminf(fmaxf(bx[3], 0.f), 14.f);
    float bw = fmaxf(x2 - x1, 1.f) * (1.0f / 3.0f);
    float bh = fmaxf(y2 - y1, 1.f) * (1.0f / 3.0f);

    int   ylo[6], xlo[6];
    float wylo[6], wyhi[6], wxlo[6], wxhi[6];
    #pragma unroll
    for (int i = 0; i < 6; ++i) {
        float off = (i & 1) ? 0.75f : 0.25f;
        float pf  = (float)(i >> 1);
        float yc = y1 + (pf + off) * bh;
        bool  vy = (yc > -1.0f) && (yc < 14.f);
        float cy = fminf(fmaxf(yc, 0.f), 13.f);
        int   lo = (int)floorf(cy); if (lo > 12) lo = 12;
        float fy = cy - (float)lo;
        ylo[i]  = lo;
        wylo[i] = vy ? 1.f - fy : 0.f;
        wyhi[i] = vy ? fy       : 0.f;
        float xc = x1 + (pf + off) * bw;
        bool  vx = (xc > -1.0f) && (xc < 14.f);
        float cx = fminf(fmaxf(xc, 0.f), 13.f);
        int   lx = (int)floorf(cx); if (lx > 12) lx = 12;
        float fx = cx - (float)lx;
        xlo[i]  = lx;
        wxlo[i] = vx ? 1.f - fx : 0.f;
        wxhi[i] = vx ? fx       : 0.f;
    }

    // ---- 36 samples, 4 corners each, fully unrolled (keep arrays in regs)
    float acc[3][3][8] = {};
    #pragma unroll
    for (int i = 0; i < 6; ++i) {
        #pragma unroll
        for (int j = 0; j < 6; ++j) {
            const int plo = ylo[i] * 14 + xlo[j];
            const float w00 = wylo[i] * wxlo[j];
            const float w01 = wylo[i] * wxhi[j];
            const float w10 = wyhi[i] * wxlo[j];
            const float w11 = wyhi[i] * wxhi[j];
            short8 v00 = *reinterpret_cast<const short8*>(&tile[plo][ch8]);
            short8 v01 = *reinterpret_cast<const short8*>(&tile[plo + 1][ch8]);
            short8 v10 = *reinterpret_cast<const short8*>(&tile[plo + 14][ch8]);
            short8 v11 = *reinterpret_cast<const short8*>(&tile[plo + 15][ch8]);
            #pragma unroll
            for (int c = 0; c < 8; ++c) {
                float a = acc[i >> 1][j >> 1][c];
                a = fmaf(bf2f((ushortT)v00[c]), w00, a);
                a = fmaf(bf2f((ushortT)v01[c]), w01, a);
                a = fmaf(bf2f((ushortT)v10[c]), w10, a);
                a = fmaf(bf2f((ushortT)v11[c]), w11, a);
                acc[i >> 1][j >> 1][c] = a;
            }
        }
    }

    // ---- write out 9 bins x 8 channels (bf16x8 stores, coalesced per box)
    ushortT* outp = pooled + (size_t)k * 9 * 1024 + c0 + ch8;
    #pragma unroll
    for (int p = 0; p < 3; ++p) {
        #pragma unroll
        for (int q = 0; q < 3; ++q) {
            short8 ov;
            #pragma unroll
            for (int c = 0; c < 8; ++c) ov[c] = (short)f2bf(acc[p][q][c] * 0.25f);
            *reinterpret_cast<short8*>(outp + (size_t)(p * 3 + q) * 1024) = ov;
        }
    }
}

// ---------------------------------------------------------------------------
// 4) MFMA GEMM (m97 structure): C[M][N] = A[M][K] * Bt[N][K]^T
// ---------------------------------------------------------------------------
template<int RELU, int BIAS>
__global__ __launch_bounds__(256)
void gemm_mfma(const ushortT* __restrict__ A, const ushortT* __restrict__ Bt,
               ushortT* __restrict__ C, const float* __restrict__ bias,
               int M, int N, int K)
{
    __shared__ ushortT As[128 * 32];
    __shared__ ushortT Bs[128 * 32];
    const int tid  = threadIdx.x;
    const int lane = tid & 63;
    const int wid  = tid >> 6;
    const int wr   = wid >> 1;
    const int wc   = wid & 1;
    const size_t row0 = (size_t)blockIdx.x * 128;
    const size_t col0 = (size_t)blockIdx.y * 128;

    const int s_row = tid >> 2;
    const int s_k   = (tid & 3) * 8;
    const ushortT* ag = A  + (row0 + s_row) * K + s_k;
    const ushortT* bg = Bt + (col0 + s_row) * K + s_k;
    ushortT* al = &As[s_row * 32 + s_k];
    ushortT* bl = &Bs[s_row * 32 + s_k];

    f32x4 acc[4][4];
    #pragma unroll
    for (int i = 0; i < 4; ++i)
        #pragma unroll
        for (int j = 0; j < 4; ++j) acc[i][j] = (f32x4){0.f, 0.f, 0.f, 0.f};

    const int fr = lane & 15;
    const int kg = (lane >> 4) * 8;

    for (int k0 = 0; k0 < K; k0 += 32) {
        gload_lds16(ag + k0,                  al);
        gload_lds16(ag + k0 + (size_t)64 * K, al + 64 * 32);
        gload_lds16(bg + k0,                  bl);
        gload_lds16(bg + k0 + (size_t)64 * K, bl + 64 * 32);
        __syncthreads();
        bf16x8 a[4], b[4];
        #pragma unroll
        for (int m = 0; m < 4; ++m)
            a[m] = *reinterpret_cast<const bf16x8*>(&As[(wr*64 + m*16 + fr) * 32 + kg]);
        #pragma unroll
        for (int n = 0; n < 4; ++n)
            b[n] = *reinterpret_cast<const bf16x8*>(&Bs[(wc*64 + n*16 + fr) * 32 + kg]);
        #pragma unroll
        for (int m = 0; m < 4; ++m)
            #pragma unroll
            for (int n = 0; n < 4; ++n)
                acc[m][n] = __builtin_amdgcn_mfma_f32_16x16x32_bf16(a[m], b[n], acc[m][n], 0, 0, 0);
        __syncthreads();
    }

    const int orow = (lane >> 4) * 4;
    #pragma unroll
    for (int n = 0; n < 4; ++n) {
        const size_t col = col0 + wc*64 + n*16 + fr;
        float bv = 0.f;
        if (BIAS) bv = bias[col];
        #pragma unroll
        for (int m = 0; m < 4; ++m) {
            const size_t rbase = row0 + wr*64 + m*16 + orow;
            #pragma unroll
            for (int j = 0; j < 4; ++j) {
                float v = acc[m][n][j] + bv;
                if (RELU) v = fmaxf(v, 0.f);
                C[(rbase + j) * N + col] = f2bf(v);
            }
        }
    }
}

// ---------------------------------------------------------------------------
// 5) fc2: out[4096][27] f32 = h[4096][1024] @ w[1024][27] + b
// ---------------------------------------------------------------------------
__global__ __launch_bounds__(64)
void fc2_kernel(const ushortT* __restrict__ h, const float* __restrict__ w,
                const float* __restrict__ bias, float* __restrict__ out)
{
    const int r    = blockIdx.x;
    const int lane = threadIdx.x;
    float acc[27];
    #pragma unroll
    for (int j = 0; j < 27; ++j) acc[j] = 0.f;
    const ushortT* hr = h + (size_t)r * 1024;
    for (int k = lane; k < 1024; k += 64) {
        float hv = bf2f(hr[k]);
        const float* wr = w + (size_t)k * 27;
        #pragma unroll
        for (int j = 0; j < 27; ++j) acc[j] = fmaf(hv, wr[j], acc[j]);
    }
    #pragma unroll
    for (int j = 0; j < 27; ++j) {
        #pragma unroll
        for (int off = 32; off; off >>= 1)
            acc[j] += __shfl_down(acc[j], off);
    }
    if (lane == 0) {
        #pragma unroll
        for (int j = 0; j < 27; ++j)
            out[(size_t)r * 27 + j] = acc[j] + bias[j];
    }
}

// ---------------------------------------------------------------------------
extern "C" void kernel_launch(void* const* d_in, const int* in_sizes, int n_in,
                              void* d_out, int out_size, void* d_ws, size_t ws_size,
                              hipStream_t stream)
{
    (void)in_sizes; (void)n_in; (void)out_size; (void)ws_size;
    const float* fmap  = (const float*)d_in[0];
    const float* boxes = (const float*)d_in[1];
    const float* w_c1  = (const float*)d_in[2];
    const float* w_c2  = (const float*)d_in[3];
    const float* w_fc1 = (const float*)d_in[4];
    const float* b_fc1 = (const float*)d_in[5];
    const float* w_fc2 = (const float*)d_in[6];
    const float* b_fc2 = (const float*)d_in[7];
    float* out = (float*)d_out;

    // Workspace (108 MB, no aliasing needed now that fT is gone):
    char* ws = (char*)d_ws;
    ushortT* pooled = (ushortT*)(ws);                             // 75,497,472
    ushortT* ybuf   = (ushortT*)(ws + 75497472);                  // 18,874,368
    ushortT* hbuf   = (ushortT*)(ws + 75497472 + 18874368);       //  8,388,608
    ushortT* Wct_t  = (ushortT*)(ws + 75497472 + 18874368 + 8388608);          // 524,288
    ushortT* wp_t   = (ushortT*)(ws + 75497472 + 18874368 + 8388608 + 524288); // 4,718,592

    hipLaunchKernelGGL(build_wct,       dim3(4, 16),  dim3(256), 0, stream, w_c1, w_c2, Wct_t);
    hipLaunchKernelGGL(permute_fc1,     dim3(36, 16), dim3(256), 0, stream, w_fc1, wp_t);
    hipLaunchKernelGGL(roi_align_fused, dim3(2048),   dim3(256), 0, stream, fmap, boxes, pooled);

    // GEMM1: [36864 x 256] = pooled[36864 x 1024] * Wct_t[256 x 1024]^T
    hipLaunchKernelGGL((gemm_mfma<0,0>), dim3(288, 2), dim3(256), 0, stream,
                       pooled, Wct_t, ybuf, (const float*)nullptr, 36864, 256, 1024);
    // GEMM2: [4096 x 1024] = ybuf[4096 x 2304] * wp_t[1024 x 2304]^T  (+bias, relu)
    hipLaunchKernelGGL((gemm_mfma<1,1>), dim3(32, 8),  dim3(256), 0, stream,
                       ybuf, wp_t, hbuf, b_fc1, 4096, 1024, 2304);
    hipLaunchKernelGGL(fc2_kernel,      dim3(4096), dim3(64), 0, stream,
                       hbuf, w_fc2, b_fc2, out);
}

// Round 5
// 177.373 us; speedup vs baseline: 4.6179x; 1.2196x over previous
//
#include <hip/hip_runtime.h>

typedef unsigned short ushortT;
typedef __attribute__((ext_vector_type(8))) short short8;
typedef __attribute__((ext_vector_type(4))) short short4v;
typedef __attribute__((ext_vector_type(8))) __bf16 bf16x8;
typedef __attribute__((ext_vector_type(4))) float f32x4;

__device__ __forceinline__ float bf2f(ushortT u) {
    unsigned int x = ((unsigned int)u) << 16;
    return __builtin_bit_cast(float, x);
}
__device__ __forceinline__ ushortT f2bf(float f) {
    unsigned int x = __builtin_bit_cast(unsigned int, f);
    unsigned int r = (x + 0x7FFFu + ((x >> 16) & 1u)) >> 16;
    return (ushortT)r;
}

__device__ __forceinline__ void gload_lds16(const void* g, void* l) {
    __builtin_amdgcn_global_load_lds(
        (const __attribute__((address_space(1))) void*)g,
        (__attribute__((address_space(3))) void*)l, 16, 0, 0);
}

// ---------------------------------------------------------------------------
// 1) Wct_t[o][c] = sum_m w_c2[o][m] * w_c1[m][c]   ([256][1024] bf16, B^T form)
// ---------------------------------------------------------------------------
__global__ __launch_bounds__(256)
void build_wct(const float* __restrict__ w_c1, const float* __restrict__ w_c2,
               ushortT* __restrict__ Wct_t)
{
    __shared__ float w2s[64][65];
    __shared__ float w1s[64][65];
    const int o0 = blockIdx.x * 64;
    const int c0 = blockIdx.y * 64;
    const int tid = threadIdx.x;
    const int ty = tid >> 4, tx = tid & 15;
    float acc[4][4] = {};
    for (int m0 = 0; m0 < 512; m0 += 64) {
        #pragma unroll
        for (int c4 = 0; c4 < 4; ++c4) {
            int idx = c4 * 256 + tid;
            int row = idx >> 4, f4 = idx & 15;
            float4 v = *reinterpret_cast<const float4*>(w_c2 + (size_t)(o0 + row) * 512 + m0 + f4 * 4);
            w2s[row][f4*4+0] = v.x; w2s[row][f4*4+1] = v.y;
            w2s[row][f4*4+2] = v.z; w2s[row][f4*4+3] = v.w;
            float4 u = *reinterpret_cast<const float4*>(w_c1 + (size_t)(m0 + row) * 1024 + c0 + f4 * 4);
            w1s[row][f4*4+0] = u.x; w1s[row][f4*4+1] = u.y;
            w1s[row][f4*4+2] = u.z; w1s[row][f4*4+3] = u.w;
        }
        __syncthreads();
        for (int m = 0; m < 64; ++m) {
            float a[4], b[4];
            #pragma unroll
            for (int i = 0; i < 4; ++i) a[i] = w2s[ty*4+i][m];
            #pragma unroll
            for (int j = 0; j < 4; ++j) b[j] = w1s[m][tx*4+j];
            #pragma unroll
            for (int i = 0; i < 4; ++i)
                #pragma unroll
                for (int j = 0; j < 4; ++j) acc[i][j] = fmaf(a[i], b[j], acc[i][j]);
        }
        __syncthreads();
    }
    #pragma unroll
    for (int i = 0; i < 4; ++i) {
        short4v ov;
        #pragma unroll
        for (int j = 0; j < 4; ++j) ov[j] = (short)f2bf(acc[i][j]);
        *reinterpret_cast<short4v*>(Wct_t + (size_t)(o0 + ty*4 + i) * 1024 + c0 + tx*4) = ov;
    }
}

// ---------------------------------------------------------------------------
// 2) wp_t[j][hw*256+o] = w_fc1[o*9+hw][j]   ([1024][2304] bf16, B^T form)
// ---------------------------------------------------------------------------
__global__ __launch_bounds__(256)
void permute_fc1(const float* __restrict__ w_fc1, ushortT* __restrict__ wpt)
{
    __shared__ float tile[64][65];
    const int ci0 = blockIdx.x * 64;
    const int j0  = blockIdx.y * 64;
    const int hw  = ci0 >> 8;
    const int o0  = ci0 & 255;
    const int tid = threadIdx.x;
    #pragma unroll
    for (int c4 = 0; c4 < 4; ++c4) {
        int idx = c4 * 256 + tid;
        int row = idx >> 4;           // o offset 0..63
        int f4  = idx & 15;
        float4 v = *reinterpret_cast<const float4*>(
            w_fc1 + (size_t)((o0 + row) * 9 + hw) * 1024 + j0 + f4 * 4);
        tile[row][f4*4+0] = v.x; tile[row][f4*4+1] = v.y;
        tile[row][f4*4+2] = v.z; tile[row][f4*4+3] = v.w;
    }
    __syncthreads();
    #pragma unroll
    for (int c4 = 0; c4 < 4; ++c4) {
        int idx = c4 * 256 + tid;
        int j   = idx >> 4;           // 0..63
        int og  = idx & 15;           // o group of 4
        short4v ov;
        #pragma unroll
        for (int i = 0; i < 4; ++i) ov[i] = (short)f2bf(tile[og*4+i][j]);
        *reinterpret_cast<short4v*>(wpt + (size_t)(j0 + j) * 2304 + ci0 + og*4) = ov;
    }
}

// ---------------------------------------------------------------------------
// 3) conv_fmap: fmap2[b][p][o] = sum_c fmap[b][c][p] * Wct_t[o][c]  (bf16 out)
//    Block = (image, pos-tile of 64); 4 waves = 4 o-groups of 64.
//    Waves 0-1 stage fmap tile transposed (4x4 reg transpose, b64 writes);
//    waves 2-3 stage Wct via global_load_lds. MFMA 16x16x32, m97 mapping.
// ---------------------------------------------------------------------------
__global__ __launch_bounds__(256)
void conv_fmap(const float* __restrict__ fmap, const ushortT* __restrict__ Wct_t,
               ushortT* __restrict__ fmap2)
{
    __shared__ ushortT Ps[64 * 40];     // [64 pos][32 c + 8 pad] rows 80B
    __shared__ ushortT Ws[256 * 32];    // [256 o][32 c] linear (gload_lds dest)
    const int tid  = threadIdx.x;
    const int wid  = tid >> 6;
    const int lane = tid & 63;
    const int b    = blockIdx.x >> 2;
    const int pt   = blockIdx.x & 3;
    const int p0   = (pt == 3) ? 132 : pt * 64;   // tiles {0,64,128,132} cover 0..195

    f32x4 acc[4][4];
    #pragma unroll
    for (int i = 0; i < 4; ++i)
        #pragma unroll
        for (int j = 0; j < 4; ++j) acc[i][j] = (f32x4){0.f, 0.f, 0.f, 0.f};

    const int fr = lane & 15;
    const int kg = (lane >> 4) * 8;

    for (int k0 = 0; k0 < 1024; k0 += 32) {
        if (wid < 2) {
            // stage B: fmap[b][k0+c4*4 .. +3][p0+pg*4 .. +3] -> Ps[p][c] transposed
            const int c4 = tid >> 4;      // 0..7
            const int pg = tid & 15;      // 0..15
            const float* srcb = fmap + ((size_t)b * 1024 + k0 + c4 * 4) * 196 + p0 + pg * 4;
            float4 v0 = *reinterpret_cast<const float4*>(srcb);
            float4 v1 = *reinterpret_cast<const float4*>(srcb + 196);
            float4 v2 = *reinterpret_cast<const float4*>(srcb + 392);
            float4 v3 = *reinterpret_cast<const float4*>(srcb + 588);
            short4v w0 = { (short)f2bf(v0.x), (short)f2bf(v1.x), (short)f2bf(v2.x), (short)f2bf(v3.x) };
            short4v w1 = { (short)f2bf(v0.y), (short)f2bf(v1.y), (short)f2bf(v2.y), (short)f2bf(v3.y) };
            short4v w2 = { (short)f2bf(v0.z), (short)f2bf(v1.z), (short)f2bf(v2.z), (short)f2bf(v3.z) };
            short4v w3 = { (short)f2bf(v0.w), (short)f2bf(v1.w), (short)f2bf(v2.w), (short)f2bf(v3.w) };
            ushortT* dst = &Ps[(pg * 4) * 40 + c4 * 4];
            *reinterpret_cast<short4v*>(dst +   0) = w0;
            *reinterpret_cast<short4v*>(dst +  40) = w1;
            *reinterpret_cast<short4v*>(dst +  80) = w2;
            *reinterpret_cast<short4v*>(dst + 120) = w3;
        } else {
            // stage A: Wct_t[o][k0..k0+31] -> Ws[o][c], 16KB via gload_lds
            const int l = tid - 128;      // 0..127
            #pragma unroll
            for (int i = 0; i < 8; ++i) {
                int chunk = l + 128 * i;  // 0..1023; lane-consecutive per instr
                gload_lds16(Wct_t + (size_t)(chunk >> 2) * 1024 + k0 + (chunk & 3) * 8,
                            &Ws[chunk * 8]);
            }
        }
        __syncthreads();
        bf16x8 a[4], w[4];
        #pragma unroll
        for (int m = 0; m < 4; ++m)
            a[m] = *reinterpret_cast<const bf16x8*>(&Ps[(m * 16 + fr) * 40 + kg]);
        #pragma unroll
        for (int n = 0; n < 4; ++n)
            w[n] = *reinterpret_cast<const bf16x8*>(&Ws[(wid * 64 + n * 16 + fr) * 32 + kg]);
        #pragma unroll
        for (int m = 0; m < 4; ++m)
            #pragma unroll
            for (int n = 0; n < 4; ++n)
                acc[m][n] = __builtin_amdgcn_mfma_f32_16x16x32_bf16(a[m], w[n], acc[m][n], 0, 0, 0);
        __syncthreads();
    }

    // D: col(lane&15)=o, row=(lane>>4)*4+j = pos  [m89/m91 mapping]
    const int orow = (lane >> 4) * 4;
    #pragma unroll
    for (int m = 0; m < 4; ++m) {
        #pragma unroll
        for (int j = 0; j < 4; ++j) {
            const size_t p = (size_t)p0 + m * 16 + orow + j;
            ushortT* dst = fmap2 + ((size_t)b * 196 + p) * 256 + wid * 64 + fr;
            #pragma unroll
            for (int n = 0; n < 4; ++n)
                dst[n * 16] = f2bf(acc[m][n][j]);
        }
    }
}

// ---------------------------------------------------------------------------
// 4) roi_lite: fmap2 bf16 [128][196][256] -> pooled [4096][9*256] bf16
//    Block = (image, 64-o group). LDS tile [196][72] (144B rows, 16B-aligned).
// ---------------------------------------------------------------------------
__global__ __launch_bounds__(256)
void roi_lite(const ushortT* __restrict__ fmap2, const float* __restrict__ boxes,
              ushortT* __restrict__ pooled)
{
    __shared__ ushortT tile[196][72];
    const int b   = blockIdx.x >> 2;
    const int o0  = (blockIdx.x & 3) << 6;
    const int tid = threadIdx.x;

    const ushortT* src = fmap2 + (size_t)b * 196 * 256 + o0;
    #pragma unroll
    for (int i = 0; i < 7; ++i) {
        int chunk = tid + (i << 8);           // 196*8 = 1568 chunks of 16B
        if (chunk < 1568) {
            int p  = chunk >> 3;
            int c8 = (chunk & 7) << 3;
            short8 v = *reinterpret_cast<const short8*>(src + (size_t)p * 256 + c8);
            *reinterpret_cast<short8*>(&tile[p][c8]) = v;
        }
    }
    __syncthreads();

    const int box = tid >> 3;          // 0..31
    const int ch8 = (tid & 7) << 3;    // 0..56
    const int k   = (b << 5) + box;
    const float* bx = boxes + (size_t)k * 4;
    float x1 = fminf(fmaxf(bx[0], 0.f), 14.f);
    float y1 = fminf(fmaxf(bx[1], 0.f), 14.f);
    float x2 = fminf(fmaxf(bx[2], 0.f), 14.f);
    float y2 = fminf(fmaxf(bx[3], 0.f), 14.f);
    float bw = fmaxf(x2 - x1, 1.f) * (1.0f / 3.0f);
    float bh = fmaxf(y2 - y1, 1.f) * (1.0f / 3.0f);

    int   ylo[6], xlo[6];
    float wylo[6], wyhi[6], wxlo[6], wxhi[6];
    #pragma unroll
    for (int i = 0; i < 6; ++i) {
        float off = (i & 1) ? 0.75f : 0.25f;
        float pf  = (float)(i >> 1);
        float yc = y1 + (pf + off) * bh;
        bool  vy = (yc > -1.0f) && (yc < 14.f);
        float cy = fminf(fmaxf(yc, 0.f), 13.f);
        int   lo = (int)floorf(cy); if (lo > 12) lo = 12;
        float fy = cy - (float)lo;
        ylo[i]  = lo;
        wylo[i] = vy ? 1.f - fy : 0.f;
        wyhi[i] = vy ? fy       : 0.f;
        float xc = x1 + (pf + off) * bw;
        bool  vx = (xc > -1.0f) && (xc < 14.f);
        float cx = fminf(fmaxf(xc, 0.f), 13.f);
        int   lx = (int)floorf(cx); if (lx > 12) lx = 12;
        float fx = cx - (float)lx;
        xlo[i]  = lx;
        wxlo[i] = vx ? 1.f - fx : 0.f;
        wxhi[i] = vx ? fx       : 0.f;
    }

    float acc[3][3][8] = {};
    #pragma unroll
    for (int i = 0; i < 6; ++i) {
        #pragma unroll
        for (int j = 0; j < 6; ++j) {
            const int plo = ylo[i] * 14 + xlo[j];
            const float w00 = wylo[i] * wxlo[j];
            const float w01 = wylo[i] * wxhi[j];
            const float w10 = wyhi[i] * wxlo[j];
            const float w11 = wyhi[i] * wxhi[j];
            short8 v00 = *reinterpret_cast<const short8*>(&tile[plo][ch8]);
            short8 v01 = *reinterpret_cast<const short8*>(&tile[plo + 1][ch8]);
            short8 v10 = *reinterpret_cast<const short8*>(&tile[plo + 14][ch8]);
            short8 v11 = *reinterpret_cast<const short8*>(&tile[plo + 15][ch8]);
            #pragma unroll
            for (int c = 0; c < 8; ++c) {
                float a = acc[i >> 1][j >> 1][c];
                a = fmaf(bf2f((ushortT)v00[c]), w00, a);
                a = fmaf(bf2f((ushortT)v01[c]), w01, a);
                a = fmaf(bf2f((ushortT)v10[c]), w10, a);
                a = fmaf(bf2f((ushortT)v11[c]), w11, a);
                acc[i >> 1][j >> 1][c] = a;
            }
        }
    }

    ushortT* outp = pooled + (size_t)k * 2304 + o0 + ch8;
    #pragma unroll
    for (int p = 0; p < 3; ++p) {
        #pragma unroll
        for (int q = 0; q < 3; ++q) {
            short8 ov;
            #pragma unroll
            for (int c = 0; c < 8; ++c) ov[c] = (short)f2bf(acc[p][q][c] * 0.25f);
            *reinterpret_cast<short8*>(outp + (size_t)(p * 3 + q) * 256) = ov;
        }
    }
}

// ---------------------------------------------------------------------------
// 5) MFMA GEMM (m97 structure): C[M][N] = A[M][K] * Bt[N][K]^T
// ---------------------------------------------------------------------------
template<int RELU, int BIAS>
__global__ __launch_bounds__(256)
void gemm_mfma(const ushortT* __restrict__ A, const ushortT* __restrict__ Bt,
               ushortT* __restrict__ C, const float* __restrict__ bias,
               int M, int N, int K)
{
    __shared__ ushortT As[128 * 32];
    __shared__ ushortT Bs[128 * 32];
    const int tid  = threadIdx.x;
    const int lane = tid & 63;
    const int wid  = tid >> 6;
    const int wr   = wid >> 1;
    const int wc   = wid & 1;
    const size_t row0 = (size_t)blockIdx.x * 128;
    const size_t col0 = (size_t)blockIdx.y * 128;

    const int s_row = tid >> 2;
    const int s_k   = (tid & 3) * 8;
    const ushortT* ag = A  + (row0 + s_row) * K + s_k;
    const ushortT* bg = Bt + (col0 + s_row) * K + s_k;
    ushortT* al = &As[s_row * 32 + s_k];
    ushortT* bl = &Bs[s_row * 32 + s_k];

    f32x4 acc[4][4];
    #pragma unroll
    for (int i = 0; i < 4; ++i)
        #pragma unroll
        for (int j = 0; j < 4; ++j) acc[i][j] = (f32x4){0.f, 0.f, 0.f, 0.f};

    const int fr = lane & 15;
    const int kg = (lane >> 4) * 8;

    for (int k0 = 0; k0 < K; k0 += 32) {
        gload_lds16(ag + k0,                  al);
        gload_lds16(ag + k0 + (size_t)64 * K, al + 64 * 32);
        gload_lds16(bg + k0,                  bl);
        gload_lds16(bg + k0 + (size_t)64 * K, bl + 64 * 32);
        __syncthreads();
        bf16x8 a[4], b[4];
        #pragma unroll
        for (int m = 0; m < 4; ++m)
            a[m] = *reinterpret_cast<const bf16x8*>(&As[(wr*64 + m*16 + fr) * 32 + kg]);
        #pragma unroll
        for (int n = 0; n < 4; ++n)
            b[n] = *reinterpret_cast<const bf16x8*>(&Bs[(wc*64 + n*16 + fr) * 32 + kg]);
        #pragma unroll
        for (int m = 0; m < 4; ++m)
            #pragma unroll
            for (int n = 0; n < 4; ++n)
                acc[m][n] = __builtin_amdgcn_mfma_f32_16x16x32_bf16(a[m], b[n], acc[m][n], 0, 0, 0);
        __syncthreads();
    }

    const int orow = (lane >> 4) * 4;
    #pragma unroll
    for (int n = 0; n < 4; ++n) {
        const size_t col = col0 + wc*64 + n*16 + fr;
        float bv = 0.f;
        if (BIAS) bv = bias[col];
        #pragma unroll
        for (int m = 0; m < 4; ++m) {
            const size_t rbase = row0 + wr*64 + m*16 + orow;
            #pragma unroll
            for (int j = 0; j < 4; ++j) {
                float v = acc[m][n][j] + bv;
                if (RELU) v = fmaxf(v, 0.f);
                C[(rbase + j) * N + col] = f2bf(v);
            }
        }
    }
}

// ---------------------------------------------------------------------------
// 6) fc2: out[4096][27] f32 = h[4096][1024] @ w[1024][27] + b
// ---------------------------------------------------------------------------
__global__ __launch_bounds__(64)
void fc2_kernel(const ushortT* __restrict__ h, const float* __restrict__ w,
                const float* __restrict__ bias, float* __restrict__ out)
{
    const int r    = blockIdx.x;
    const int lane = threadIdx.x;
    float acc[27];
    #pragma unroll
    for (int j = 0; j < 27; ++j) acc[j] = 0.f;
    const ushortT* hr = h + (size_t)r * 1024;
    for (int k = lane; k < 1024; k += 64) {
        float hv = bf2f(hr[k]);
        const float* wr = w + (size_t)k * 27;
        #pragma unroll
        for (int j = 0; j < 27; ++j) acc[j] = fmaf(hv, wr[j], acc[j]);
    }
    #pragma unroll
    for (int j = 0; j < 27; ++j) {
        #pragma unroll
        for (int off = 32; off; off >>= 1)
            acc[j] += __shfl_down(acc[j], off);
    }
    if (lane == 0) {
        #pragma unroll
        for (int j = 0; j < 27; ++j)
            out[(size_t)r * 27 + j] = acc[j] + bias[j];
    }
}

// ---------------------------------------------------------------------------
extern "C" void kernel_launch(void* const* d_in, const int* in_sizes, int n_in,
                              void* d_out, int out_size, void* d_ws, size_t ws_size,
                              hipStream_t stream)
{
    (void)in_sizes; (void)n_in; (void)out_size; (void)ws_size;
    const float* fmap  = (const float*)d_in[0];
    const float* boxes = (const float*)d_in[1];
    const float* w_c1  = (const float*)d_in[2];
    const float* w_c2  = (const float*)d_in[3];
    const float* w_fc1 = (const float*)d_in[4];
    const float* b_fc1 = (const float*)d_in[5];
    const float* w_fc2 = (const float*)d_in[6];
    const float* b_fc2 = (const float*)d_in[7];
    float* out = (float*)d_out;

    // Workspace (~45.4 MB):
    char* ws = (char*)d_ws;
    ushortT* fmap2  = (ushortT*)(ws);                                  // 12,845,056
    ushortT* pooled = (ushortT*)(ws + 12845056);                       // 18,874,368
    ushortT* hbuf   = (ushortT*)(ws + 12845056 + 18874368);            //  8,388,608
    ushortT* Wct_t  = (ushortT*)(ws + 12845056 + 18874368 + 8388608);  //    524,288
    ushortT* wp_t   = (ushortT*)(ws + 12845056 + 18874368 + 8388608 + 524288); // 4,718,592

    hipLaunchKernelGGL(build_wct,   dim3(4, 16),  dim3(256), 0, stream, w_c1, w_c2, Wct_t);
    hipLaunchKernelGGL(permute_fc1, dim3(36, 16), dim3(256), 0, stream, w_fc1, wp_t);
    // conv first (channel mixing commutes with ROIAlign)
    hipLaunchKernelGGL(conv_fmap,   dim3(512),    dim3(256), 0, stream, fmap, Wct_t, fmap2);
    hipLaunchKernelGGL(roi_lite,    dim3(512),    dim3(256), 0, stream, fmap2, boxes, pooled);
    // GEMM2: [4096 x 1024] = pooled[4096 x 2304] * wp_t[1024 x 2304]^T  (+bias, relu)
    hipLaunchKernelGGL((gemm_mfma<1,1>), dim3(32, 8), dim3(256), 0, stream,
                       pooled, wp_t, hbuf, b_fc1, 4096, 1024, 2304);
    hipLaunchKernelGGL(fc2_kernel,  dim3(4096), dim3(64), 0, stream,
                       hbuf, w_fc2, b_fc2, out);
}

// Round 6
// 169.022 us; speedup vs baseline: 4.8461x; 1.0494x over previous
//
#include <hip/hip_runtime.h>

typedef unsigned short ushortT;
typedef __attribute__((ext_vector_type(8))) short short8;
typedef __attribute__((ext_vector_type(4))) short short4v;
typedef __attribute__((ext_vector_type(8))) __bf16 bf16x8;
typedef __attribute__((ext_vector_type(4))) float f32x4;

__device__ __forceinline__ float bf2f(ushortT u) {
    unsigned int x = ((unsigned int)u) << 16;
    return __builtin_bit_cast(float, x);
}
__device__ __forceinline__ ushortT f2bf(float f) {
    unsigned int x = __builtin_bit_cast(unsigned int, f);
    unsigned int r = (x + 0x7FFFu + ((x >> 16) & 1u)) >> 16;
    return (ushortT)r;
}

__device__ __forceinline__ void gload_lds16(const void* g, void* l) {
    __builtin_amdgcn_global_load_lds(
        (const __attribute__((address_space(1))) void*)g,
        (__attribute__((address_space(3))) void*)l, 16, 0, 0);
}

// ---------------------------------------------------------------------------
// 1) Wct_t[o][c] = sum_m w_c2[o][m] * w_c1[m][c]   ([256][1024] bf16, B^T form)
// ---------------------------------------------------------------------------
__global__ __launch_bounds__(256)
void build_wct(const float* __restrict__ w_c1, const float* __restrict__ w_c2,
               ushortT* __restrict__ Wct_t)
{
    __shared__ float w2s[64][65];
    __shared__ float w1s[64][65];
    const int o0 = blockIdx.x * 64;
    const int c0 = blockIdx.y * 64;
    const int tid = threadIdx.x;
    const int ty = tid >> 4, tx = tid & 15;
    float acc[4][4] = {};
    for (int m0 = 0; m0 < 512; m0 += 64) {
        #pragma unroll
        for (int c4 = 0; c4 < 4; ++c4) {
            int idx = c4 * 256 + tid;
            int row = idx >> 4, f4 = idx & 15;
            float4 v = *reinterpret_cast<const float4*>(w_c2 + (size_t)(o0 + row) * 512 + m0 + f4 * 4);
            w2s[row][f4*4+0] = v.x; w2s[row][f4*4+1] = v.y;
            w2s[row][f4*4+2] = v.z; w2s[row][f4*4+3] = v.w;
            float4 u = *reinterpret_cast<const float4*>(w_c1 + (size_t)(m0 + row) * 1024 + c0 + f4 * 4);
            w1s[row][f4*4+0] = u.x; w1s[row][f4*4+1] = u.y;
            w1s[row][f4*4+2] = u.z; w1s[row][f4*4+3] = u.w;
        }
        __syncthreads();
        for (int m = 0; m < 64; ++m) {
            float a[4], b[4];
            #pragma unroll
            for (int i = 0; i < 4; ++i) a[i] = w2s[ty*4+i][m];
            #pragma unroll
            for (int j = 0; j < 4; ++j) b[j] = w1s[m][tx*4+j];
            #pragma unroll
            for (int i = 0; i < 4; ++i)
                #pragma unroll
                for (int j = 0; j < 4; ++j) acc[i][j] = fmaf(a[i], b[j], acc[i][j]);
        }
        __syncthreads();
    }
    #pragma unroll
    for (int i = 0; i < 4; ++i) {
        short4v ov;
        #pragma unroll
        for (int j = 0; j < 4; ++j) ov[j] = (short)f2bf(acc[i][j]);
        *reinterpret_cast<short4v*>(Wct_t + (size_t)(o0 + ty*4 + i) * 1024 + c0 + tx*4) = ov;
    }
}

// ---------------------------------------------------------------------------
// 2) wp_t[j][hw*256+o] = w_fc1[o*9+hw][j]   ([1024][2304] bf16, B^T form)
// ---------------------------------------------------------------------------
__global__ __launch_bounds__(256)
void permute_fc1(const float* __restrict__ w_fc1, ushortT* __restrict__ wpt)
{
    __shared__ float tile[64][65];
    const int ci0 = blockIdx.x * 64;
    const int j0  = blockIdx.y * 64;
    const int hw  = ci0 >> 8;
    const int o0  = ci0 & 255;
    const int tid = threadIdx.x;
    #pragma unroll
    for (int c4 = 0; c4 < 4; ++c4) {
        int idx = c4 * 256 + tid;
        int row = idx >> 4;           // o offset 0..63
        int f4  = idx & 15;
        float4 v = *reinterpret_cast<const float4*>(
            w_fc1 + (size_t)((o0 + row) * 9 + hw) * 1024 + j0 + f4 * 4);
        tile[row][f4*4+0] = v.x; tile[row][f4*4+1] = v.y;
        tile[row][f4*4+2] = v.z; tile[row][f4*4+3] = v.w;
    }
    __syncthreads();
    #pragma unroll
    for (int c4 = 0; c4 < 4; ++c4) {
        int idx = c4 * 256 + tid;
        int j   = idx >> 4;           // 0..63
        int og  = idx & 15;           // o group of 4
        short4v ov;
        #pragma unroll
        for (int i = 0; i < 4; ++i) ov[i] = (short)f2bf(tile[og*4+i][j]);
        *reinterpret_cast<short4v*>(wpt + (size_t)(j0 + j) * 2304 + ci0 + og*4) = ov;
    }
}

// ---------------------------------------------------------------------------
// 3) conv_fmap v2: fmap2[b][p][o] = sum_c fmap[b][c][p] * Wct_t[o][c]
//    Double-buffered LDS + prefetch (T3 2-phase): issue next-step loads
//    before MFMA on current step; single barrier per k-step.
// ---------------------------------------------------------------------------
__global__ __launch_bounds__(256)
void conv_fmap(const float* __restrict__ fmap, const ushortT* __restrict__ Wct_t,
               ushortT* __restrict__ fmap2)
{
    __shared__ ushortT Ps[2][64 * 40];     // [64 pos][32 c + 8 pad]
    __shared__ ushortT Ws[2][256 * 32];    // [256 o][32 c] linear (gload dest)
    const int tid  = threadIdx.x;
    const int wid  = tid >> 6;
    const int lane = tid & 63;
    const int b    = blockIdx.x >> 2;
    const int pt   = blockIdx.x & 3;
    const int p0   = (pt == 3) ? 132 : pt * 64;   // tiles {0,64,128,132}

    const int c4 = tid >> 4;      // 0..7  (valid wid<2)
    const int pg = tid & 15;      // 0..15 (valid wid<2)
    const int wl = tid - 128;     // 0..127 (valid wid>=2)

    float4 pv0, pv1, pv2, pv3;

    auto loadP = [&](int k0) {
        const float* srcb = fmap + ((size_t)b * 1024 + k0 + c4 * 4) * 196 + p0 + pg * 4;
        pv0 = *reinterpret_cast<const float4*>(srcb);
        pv1 = *reinterpret_cast<const float4*>(srcb + 196);
        pv2 = *reinterpret_cast<const float4*>(srcb + 392);
        pv3 = *reinterpret_cast<const float4*>(srcb + 588);
    };
    auto writeP = [&](ushortT* Pb) {
        short4v w0 = { (short)f2bf(pv0.x), (short)f2bf(pv1.x), (short)f2bf(pv2.x), (short)f2bf(pv3.x) };
        short4v w1 = { (short)f2bf(pv0.y), (short)f2bf(pv1.y), (short)f2bf(pv2.y), (short)f2bf(pv3.y) };
        short4v w2 = { (short)f2bf(pv0.z), (short)f2bf(pv1.z), (short)f2bf(pv2.z), (short)f2bf(pv3.z) };
        short4v w3 = { (short)f2bf(pv0.w), (short)f2bf(pv1.w), (short)f2bf(pv2.w), (short)f2bf(pv3.w) };
        ushortT* dst = Pb + (pg * 4) * 40 + c4 * 4;
        *reinterpret_cast<short4v*>(dst +   0) = w0;
        *reinterpret_cast<short4v*>(dst +  40) = w1;
        *reinterpret_cast<short4v*>(dst +  80) = w2;
        *reinterpret_cast<short4v*>(dst + 120) = w3;
    };
    auto loadW = [&](int k0, ushortT* Wb) {
        #pragma unroll
        for (int i = 0; i < 8; ++i) {
            int chunk = wl + 128 * i;     // 0..1023
            gload_lds16(Wct_t + (size_t)(chunk >> 2) * 1024 + k0 + (chunk & 3) * 8,
                        Wb + chunk * 8);
        }
    };

    f32x4 acc[4][4];
    #pragma unroll
    for (int i = 0; i < 4; ++i)
        #pragma unroll
        for (int j = 0; j < 4; ++j) acc[i][j] = (f32x4){0.f, 0.f, 0.f, 0.f};

    const int fr = lane & 15;
    const int kg = (lane >> 4) * 8;

    // prologue: fill buffer 0
    if (wid < 2) { loadP(0); writeP(Ps[0]); }
    else         { loadW(0, Ws[0]); }
    __syncthreads();

    for (int t = 0; t < 32; ++t) {
        const int cur = t & 1, nxt = cur ^ 1;
        if (t < 31) {
            if (wid < 2) loadP((t + 1) * 32);      // regs; vmcnt waits at writeP
            else         loadW((t + 1) * 32, Ws[nxt]);  // in flight across MFMA
        }
        bf16x8 a[4], w[4];
        #pragma unroll
        for (int m = 0; m < 4; ++m)
            a[m] = *reinterpret_cast<const bf16x8*>(&Ps[cur][(m * 16 + fr) * 40 + kg]);
        #pragma unroll
        for (int n = 0; n < 4; ++n)
            w[n] = *reinterpret_cast<const bf16x8*>(&Ws[cur][(wid * 64 + n * 16 + fr) * 32 + kg]);
        #pragma unroll
        for (int m = 0; m < 4; ++m)
            #pragma unroll
            for (int n = 0; n < 4; ++n)
                acc[m][n] = __builtin_amdgcn_mfma_f32_16x16x32_bf16(a[m], w[n], acc[m][n], 0, 0, 0);
        if (t < 31 && wid < 2) writeP(Ps[nxt]);
        __syncthreads();
    }

    // D: col(lane&15)=o, row=(lane>>4)*4+j = pos  [m89/m91 mapping]
    const int orow = (lane >> 4) * 4;
    #pragma unroll
    for (int m = 0; m < 4; ++m) {
        #pragma unroll
        for (int j = 0; j < 4; ++j) {
            const size_t p = (size_t)p0 + m * 16 + orow + j;
            ushortT* dst = fmap2 + ((size_t)b * 196 + p) * 256 + wid * 64 + fr;
            #pragma unroll
            for (int n = 0; n < 4; ++n)
                dst[n * 16] = f2bf(acc[m][n][j]);
        }
    }
}

// ---------------------------------------------------------------------------
// 4) roi_lite: fmap2 bf16 [128][196][256] -> pooled [4096][9*256] bf16
// ---------------------------------------------------------------------------
__global__ __launch_bounds__(256)
void roi_lite(const ushortT* __restrict__ fmap2, const float* __restrict__ boxes,
              ushortT* __restrict__ pooled)
{
    __shared__ ushortT tile[196][72];
    const int b   = blockIdx.x >> 2;
    const int o0  = (blockIdx.x & 3) << 6;
    const int tid = threadIdx.x;

    const ushortT* src = fmap2 + (size_t)b * 196 * 256 + o0;
    #pragma unroll
    for (int i = 0; i < 7; ++i) {
        int chunk = tid + (i << 8);
        if (chunk < 1568) {
            int p  = chunk >> 3;
            int c8 = (chunk & 7) << 3;
            short8 v = *reinterpret_cast<const short8*>(src + (size_t)p * 256 + c8);
            *reinterpret_cast<short8*>(&tile[p][c8]) = v;
        }
    }
    __syncthreads();

    const int box = tid >> 3;
    const int ch8 = (tid & 7) << 3;
    const int k   = (b << 5) + box;
    const float* bx = boxes + (size_t)k * 4;
    float x1 = fminf(fmaxf(bx[0], 0.f), 14.f);
    float y1 = fminf(fmaxf(bx[1], 0.f), 14.f);
    float x2 = fminf(fmaxf(bx[2], 0.f), 14.f);
    float y2 = fminf(fmaxf(bx[3], 0.f), 14.f);
    float bw = fmaxf(x2 - x1, 1.f) * (1.0f / 3.0f);
    float bh = fmaxf(y2 - y1, 1.f) * (1.0f / 3.0f);

    int   ylo[6], xlo[6];
    float wylo[6], wyhi[6], wxlo[6], wxhi[6];
    #pragma unroll
    for (int i = 0; i < 6; ++i) {
        float off = (i & 1) ? 0.75f : 0.25f;
        float pf  = (float)(i >> 1);
        float yc = y1 + (pf + off) * bh;
        bool  vy = (yc > -1.0f) && (yc < 14.f);
        float cy = fminf(fmaxf(yc, 0.f), 13.f);
        int   lo = (int)floorf(cy); if (lo > 12) lo = 12;
        float fy = cy - (float)lo;
        ylo[i]  = lo;
        wylo[i] = vy ? 1.f - fy : 0.f;
        wyhi[i] = vy ? fy       : 0.f;
        float xc = x1 + (pf + off) * bw;
        bool  vx = (xc > -1.0f) && (xc < 14.f);
        float cx = fminf(fmaxf(xc, 0.f), 13.f);
        int   lx = (int)floorf(cx); if (lx > 12) lx = 12;
        float fx = cx - (float)lx;
        xlo[i]  = lx;
        wxlo[i] = vx ? 1.f - fx : 0.f;
        wxhi[i] = vx ? fx       : 0.f;
    }

    float acc[3][3][8] = {};
    #pragma unroll
    for (int i = 0; i < 6; ++i) {
        #pragma unroll
        for (int j = 0; j < 6; ++j) {
            const int plo = ylo[i] * 14 + xlo[j];
            const float w00 = wylo[i] * wxlo[j];
            const float w01 = wylo[i] * wxhi[j];
            const float w10 = wyhi[i] * wxlo[j];
            const float w11 = wyhi[i] * wxhi[j];
            short8 v00 = *reinterpret_cast<const short8*>(&tile[plo][ch8]);
            short8 v01 = *reinterpret_cast<const short8*>(&tile[plo + 1][ch8]);
            short8 v10 = *reinterpret_cast<const short8*>(&tile[plo + 14][ch8]);
            short8 v11 = *reinterpret_cast<const short8*>(&tile[plo + 15][ch8]);
            #pragma unroll
            for (int c = 0; c < 8; ++c) {
                float a = acc[i >> 1][j >> 1][c];
                a = fmaf(bf2f((ushortT)v00[c]), w00, a);
                a = fmaf(bf2f((ushortT)v01[c]), w01, a);
                a = fmaf(bf2f((ushortT)v10[c]), w10, a);
                a = fmaf(bf2f((ushortT)v11[c]), w11, a);
                acc[i >> 1][j >> 1][c] = a;
            }
        }
    }

    ushortT* outp = pooled + (size_t)k * 2304 + o0 + ch8;
    #pragma unroll
    for (int p = 0; p < 3; ++p) {
        #pragma unroll
        for (int q = 0; q < 3; ++q) {
            short8 ov;
            #pragma unroll
            for (int c = 0; c < 8; ++c) ov[c] = (short)f2bf(acc[p][q][c] * 0.25f);
            *reinterpret_cast<short8*>(outp + (size_t)(p * 3 + q) * 256) = ov;
        }
    }
}

// ---------------------------------------------------------------------------
// 5) MFMA GEMM v2 (m97 + dbuf prefetch): C[M][N] = A[M][K] * Bt[N][K]^T
// ---------------------------------------------------------------------------
template<int RELU, int BIAS>
__global__ __launch_bounds__(256)
void gemm_mfma(const ushortT* __restrict__ A, const ushortT* __restrict__ Bt,
               ushortT* __restrict__ C, const float* __restrict__ bias,
               int M, int N, int K)
{
    __shared__ ushortT As[2][128 * 32];
    __shared__ ushortT Bs[2][128 * 32];
    const int tid  = threadIdx.x;
    const int lane = tid & 63;
    const int wid  = tid >> 6;
    const int wr   = wid >> 1;
    const int wc   = wid & 1;
    const size_t row0 = (size_t)blockIdx.x * 128;
    const size_t col0 = (size_t)blockIdx.y * 128;

    const int s_row = tid >> 2;
    const int s_k   = (tid & 3) * 8;
    const int s_off = s_row * 32 + s_k;
    const ushortT* ag = A  + (row0 + s_row) * K + s_k;
    const ushortT* bg = Bt + (col0 + s_row) * K + s_k;

    auto stage = [&](int k0, int buf) {
        gload_lds16(ag + k0,                  As[buf] + s_off);
        gload_lds16(ag + k0 + (size_t)64 * K, As[buf] + s_off + 64 * 32);
        gload_lds16(bg + k0,                  Bs[buf] + s_off);
        gload_lds16(bg + k0 + (size_t)64 * K, Bs[buf] + s_off + 64 * 32);
    };

    f32x4 acc[4][4];
    #pragma unroll
    for (int i = 0; i < 4; ++i)
        #pragma unroll
        for (int j = 0; j < 4; ++j) acc[i][j] = (f32x4){0.f, 0.f, 0.f, 0.f};

    const int fr = lane & 15;
    const int kg = (lane >> 4) * 8;
    const int nsteps = K >> 5;

    stage(0, 0);
    __syncthreads();

    for (int t = 0; t < nsteps; ++t) {
        const int cur = t & 1, nxt = cur ^ 1;
        if (t + 1 < nsteps) stage((t + 1) * 32, nxt);   // in flight across MFMA
        bf16x8 a[4], b[4];
        #pragma unroll
        for (int m = 0; m < 4; ++m)
            a[m] = *reinterpret_cast<const bf16x8*>(&As[cur][(wr*64 + m*16 + fr) * 32 + kg]);
        #pragma unroll
        for (int n = 0; n < 4; ++n)
            b[n] = *reinterpret_cast<const bf16x8*>(&Bs[cur][(wc*64 + n*16 + fr) * 32 + kg]);
        #pragma unroll
        for (int m = 0; m < 4; ++m)
            #pragma unroll
            for (int n = 0; n < 4; ++n)
                acc[m][n] = __builtin_amdgcn_mfma_f32_16x16x32_bf16(a[m], b[n], acc[m][n], 0, 0, 0);
        __syncthreads();
    }

    const int orow = (lane >> 4) * 4;
    #pragma unroll
    for (int n = 0; n < 4; ++n) {
        const size_t col = col0 + wc*64 + n*16 + fr;
        float bv = 0.f;
        if (BIAS) bv = bias[col];
        #pragma unroll
        for (int m = 0; m < 4; ++m) {
            const size_t rbase = row0 + wr*64 + m*16 + orow;
            #pragma unroll
            for (int j = 0; j < 4; ++j) {
                float v = acc[m][n][j] + bv;
                if (RELU) v = fmaxf(v, 0.f);
                C[(rbase + j) * N + col] = f2bf(v);
            }
        }
    }
}

// ---------------------------------------------------------------------------
// 6) fc2 v2: out[4096][27] f32 = h[4096][1024] @ w[1024][27] + b
//    Block = 16 rows x 256 threads; w + h tiles staged in LDS.
// ---------------------------------------------------------------------------
__global__ __launch_bounds__(256)
void fc2_kernel(const ushortT* __restrict__ h, const float* __restrict__ w,
                const float* __restrict__ bias, float* __restrict__ out)
{
    __shared__ float   Wsm[128][32];     // j padded to 32 (27..31 = 0)
    __shared__ ushortT Hs[16][136];      // stride 272B: 16B-aligned, banks spread
    const int tid  = threadIdx.x;
    const int row0 = blockIdx.x * 16;
    const int r    = tid >> 4;
    const int jg   = tid & 15;
    float accx = 0.f, accy = 0.f;

    const int kk2  = tid >> 1;
    const int half = tid & 1;

    for (int k0 = 0; k0 < 1024; k0 += 128) {
        if (half == 0) {
            #pragma unroll
            for (int j = 0; j < 14; ++j)
                Wsm[kk2][j] = w[(size_t)(k0 + kk2) * 27 + j];
        } else {
            #pragma unroll
            for (int j = 14; j < 27; ++j)
                Wsm[kk2][j] = w[(size_t)(k0 + kk2) * 27 + j];
            #pragma unroll
            for (int j = 27; j < 32; ++j) Wsm[kk2][j] = 0.f;
        }
        {
            int hr = tid >> 4, hc = tid & 15;
            short8 v = *reinterpret_cast<const short8*>(
                h + (size_t)(row0 + hr) * 1024 + k0 + hc * 8);
            *reinterpret_cast<short8*>(&Hs[hr][hc * 8]) = v;
        }
        __syncthreads();
        #pragma unroll 8
        for (int kk = 0; kk < 128; ++kk) {
            float  hv = bf2f(Hs[r][kk]);
            float2 wv = *reinterpret_cast<const float2*>(&Wsm[kk][jg * 2]);
            accx = fmaf(hv, wv.x, accx);
            accy = fmaf(hv, wv.y, accy);
        }
        __syncthreads();
    }
    const int j0 = jg * 2;
    float* op = out + (size_t)(row0 + r) * 27;
    if (j0 < 27)     op[j0]     = accx + bias[j0];
    if (j0 + 1 < 27) op[j0 + 1] = accy + bias[j0 + 1];
}

// ---------------------------------------------------------------------------
extern "C" void kernel_launch(void* const* d_in, const int* in_sizes, int n_in,
                              void* d_out, int out_size, void* d_ws, size_t ws_size,
                              hipStream_t stream)
{
    (void)in_sizes; (void)n_in; (void)out_size; (void)ws_size;
    const float* fmap  = (const float*)d_in[0];
    const float* boxes = (const float*)d_in[1];
    const float* w_c1  = (const float*)d_in[2];
    const float* w_c2  = (const float*)d_in[3];
    const float* w_fc1 = (const float*)d_in[4];
    const float* b_fc1 = (const float*)d_in[5];
    const float* w_fc2 = (const float*)d_in[6];
    const float* b_fc2 = (const float*)d_in[7];
    float* out = (float*)d_out;

    // Workspace (~45.4 MB):
    char* ws = (char*)d_ws;
    ushortT* fmap2  = (ushortT*)(ws);                                  // 12,845,056
    ushortT* pooled = (ushortT*)(ws + 12845056);                       // 18,874,368
    ushortT* hbuf   = (ushortT*)(ws + 12845056 + 18874368);            //  8,388,608
    ushortT* Wct_t  = (ushortT*)(ws + 12845056 + 18874368 + 8388608);  //    524,288
    ushortT* wp_t   = (ushortT*)(ws + 12845056 + 18874368 + 8388608 + 524288); // 4,718,592

    hipLaunchKernelGGL(build_wct,   dim3(4, 16),  dim3(256), 0, stream, w_c1, w_c2, Wct_t);
    hipLaunchKernelGGL(permute_fc1, dim3(36, 16), dim3(256), 0, stream, w_fc1, wp_t);
    hipLaunchKernelGGL(conv_fmap,   dim3(512),    dim3(256), 0, stream, fmap, Wct_t, fmap2);
    hipLaunchKernelGGL(roi_lite,    dim3(512),    dim3(256), 0, stream, fmap2, boxes, pooled);
    hipLaunchKernelGGL((gemm_mfma<1,1>), dim3(32, 8), dim3(256), 0, stream,
                       pooled, wp_t, hbuf, b_fc1, 4096, 1024, 2304);
    hipLaunchKernelGGL(fc2_kernel,  dim3(256), dim3(256), 0, stream,
                       hbuf, w_fc2, b_fc2, out);
}